// Round 1
// baseline (1226.745 us; speedup 1.0000x reference)
//
#include <hip/hip_runtime.h>
#include <math.h>

#define DIMC   1024
#define NHEADS 16
#define HDIM   64
#define BATCH  2
#define SEQ    2048
#define SCALE  0.125f

#define MTOT   (BATCH * SEQ)          // 4096 rows
#define QKVN   (3 * DIMC)             // 3072
#define HEADSZ ((size_t)SEQ * HDIM)   // 131072 floats per head
#define QKVSZ  ((size_t)BATCH * NHEADS * SEQ * HDIM)  // 4194304 floats per tensor

// ---------------------------------------------------------------------------
// Kernel 1: qkv = x @ w_qkv^T + b_qkv, scattered into Q/K/V [B,H,N,D]
// 64x64 tile, BK=16, 256 threads, 4x4 microtile. fp32.
// ---------------------------------------------------------------------------
__global__ __launch_bounds__(256) void qkv_gemm(
    const float* __restrict__ x,     // [4096][1024]
    const float* __restrict__ w,     // [3072][1024]
    const float* __restrict__ bias,  // [3072]
    float* __restrict__ qkv_out)     // ws: Q|K|V each [B,H,N,D]
{
    __shared__ float As[16][68];
    __shared__ float Bs[16][68];
    const int tid = threadIdx.x;
    const int tx = tid & 15, ty = tid >> 4;
    const int m0 = blockIdx.y * 64;
    const int j0 = blockIdx.x * 64;
    const int lr = tid >> 2;          // 0..63: tile row for staging loads
    const int lk = (tid & 3) * 4;     // k-segment within BK

    float acc[4][4] = {};

    for (int k0 = 0; k0 < DIMC; k0 += 16) {
        float4 av = *(const float4*)&x[(size_t)(m0 + lr) * DIMC + k0 + lk];
        float4 bv = *(const float4*)&w[(size_t)(j0 + lr) * DIMC + k0 + lk];
        __syncthreads();  // prev-iter LDS reads complete
        As[lk + 0][lr] = av.x; As[lk + 1][lr] = av.y;
        As[lk + 2][lr] = av.z; As[lk + 3][lr] = av.w;
        Bs[lk + 0][lr] = bv.x; Bs[lk + 1][lr] = bv.y;
        Bs[lk + 2][lr] = bv.z; Bs[lk + 3][lr] = bv.w;
        __syncthreads();
#pragma unroll
        for (int kk = 0; kk < 16; ++kk) {
            float4 a = *(const float4*)&As[kk][ty * 4];
            float4 b = *(const float4*)&Bs[kk][tx * 4];
            float ar[4] = {a.x, a.y, a.z, a.w};
            float br[4] = {b.x, b.y, b.z, b.w};
#pragma unroll
            for (int ii = 0; ii < 4; ++ii)
#pragma unroll
                for (int jj = 0; jj < 4; ++jj)
                    acc[ii][jj] += ar[ii] * br[jj];
        }
    }

    // Epilogue: bias + scatter. All 4 consecutive j share s,h (j0,tx*4 are
    // multiples of 4 within a 64-aligned column block), d consecutive -> float4.
    const int j = j0 + tx * 4;
    const int s = j >> 10;            // 0:q 1:k 2:v
    const int r = j & 1023;
    const int h = r >> 6;
    const int dcol = r & 63;
    const float4 bb = *(const float4*)&bias[j];
#pragma unroll
    for (int ii = 0; ii < 4; ++ii) {
        const int m = m0 + ty * 4 + ii;
        const int b = m >> 11;        // /SEQ
        const int n = m & 2047;
        float4 o = make_float4(acc[ii][0] + bb.x, acc[ii][1] + bb.y,
                               acc[ii][2] + bb.z, acc[ii][3] + bb.w);
        size_t base = (size_t)s * QKVSZ +
                      ((size_t)(b * NHEADS + h) * SEQ + n) * HDIM + dcol;
        *(float4*)&qkv_out[base] = o;
    }
}

// ---------------------------------------------------------------------------
// Kernel 2: flash attention, fp32. Block = 256 threads handles 32 queries of
// one (b,h); iterates keys in tiles of 64 with online softmax.
// Thread map: q = tid/8 (0..31), i = tid%8. Scores: keys k = j*8+i (j=0..7).
// PV: dims d = i*8..i*8+7.
// ---------------------------------------------------------------------------
__global__ __launch_bounds__(256) void attn_kernel(
    const float* __restrict__ ws,    // Q|K|V
    float* __restrict__ ao)          // [B,N,C] attention output
{
    const float* Q = ws;
    const float* K = ws + QKVSZ;
    const float* V = ws + 2 * QKVSZ;

    __shared__ float Ks[64][68];
    __shared__ float Vs[64][68];
    __shared__ float Qs[32][68];
    __shared__ float Ss[32][65];

    const int tid = threadIdx.x;
    const int q0 = blockIdx.x * 32;
    const int h  = blockIdx.y;
    const int b  = blockIdx.z;
    const size_t headoff = (size_t)(b * NHEADS + h) * HEADSZ;
    const float* Qh = Q + headoff;
    const float* Kh = K + headoff;
    const float* Vh = V + headoff;

    // Stage Q tile (coalesced), then register-cache each thread's row.
    {
        const int qr = tid >> 3;
        const int ds = (tid & 7) * 8;
        float4 v0 = *(const float4*)&Qh[(size_t)(q0 + qr) * HDIM + ds];
        float4 v1 = *(const float4*)&Qh[(size_t)(q0 + qr) * HDIM + ds + 4];
        *(float4*)&Qs[qr][ds] = v0;
        *(float4*)&Qs[qr][ds + 4] = v1;
    }
    __syncthreads();

    const int q = tid >> 3;
    const int i = tid & 7;
    const int d8 = i * 8;

    float4 qreg[16];
#pragma unroll
    for (int u = 0; u < 16; ++u) qreg[u] = *(const float4*)&Qs[q][u * 4];

    float m_i = -1e30f, l_i = 0.f;
    float O[8] = {};

    for (int k0 = 0; k0 < SEQ; k0 += 64) {
        __syncthreads();  // prev tile's Ss/Vs reads complete
        {
            const int kr = tid >> 2;
            const int ds = (tid & 3) * 16;
#pragma unroll
            for (int u = 0; u < 4; ++u) {
                float4 kv = *(const float4*)&Kh[(size_t)(k0 + kr) * HDIM + ds + u * 4];
                float4 vv = *(const float4*)&Vh[(size_t)(k0 + kr) * HDIM + ds + u * 4];
                *(float4*)&Ks[kr][ds + u * 4] = kv;
                *(float4*)&Vs[kr][ds + u * 4] = vv;
            }
        }
        __syncthreads();

        // Scores for keys j*8+i (row spacing 1 within i -> conflict-free)
        float sc[8];
#pragma unroll
        for (int j = 0; j < 8; ++j) {
            const float* krow = &Ks[j * 8 + i][0];
            float s0 = 0.f, s1 = 0.f, s2 = 0.f, s3 = 0.f;
#pragma unroll
            for (int u = 0; u < 16; ++u) {
                float4 kv = *(const float4*)&krow[u * 4];
                s0 += qreg[u].x * kv.x;
                s1 += qreg[u].y * kv.y;
                s2 += qreg[u].z * kv.z;
                s3 += qreg[u].w * kv.w;
            }
            sc[j] = (s0 + s1 + s2 + s3) * SCALE;
        }

        float tmax = sc[0];
#pragma unroll
        for (int j = 1; j < 8; ++j) tmax = fmaxf(tmax, sc[j]);
        tmax = fmaxf(tmax, __shfl_xor(tmax, 1));
        tmax = fmaxf(tmax, __shfl_xor(tmax, 2));
        tmax = fmaxf(tmax, __shfl_xor(tmax, 4));

        const float m_new = fmaxf(m_i, tmax);
        const float alpha = __expf(m_i - m_new);
        float psum = 0.f;
#pragma unroll
        for (int j = 0; j < 8; ++j) {
            float p = __expf(sc[j] - m_new);
            psum += p;
            Ss[q][j * 8 + i] = p;
        }
        psum += __shfl_xor(psum, 1);
        psum += __shfl_xor(psum, 2);
        psum += __shfl_xor(psum, 4);
        l_i = l_i * alpha + psum;
        m_i = m_new;
        __syncthreads();  // Ss visible to all lanes of this q

#pragma unroll
        for (int c = 0; c < 8; ++c) O[c] *= alpha;
        for (int k = 0; k < 64; ++k) {
            const float p = Ss[q][k];
            float4 v0 = *(const float4*)&Vs[k][d8];
            float4 v1 = *(const float4*)&Vs[k][d8 + 4];
            O[0] += p * v0.x; O[1] += p * v0.y; O[2] += p * v0.z; O[3] += p * v0.w;
            O[4] += p * v1.x; O[5] += p * v1.y; O[6] += p * v1.z; O[7] += p * v1.w;
        }
    }

    const float inv = 1.f / l_i;
    float4 o0 = make_float4(O[0] * inv, O[1] * inv, O[2] * inv, O[3] * inv);
    float4 o1 = make_float4(O[4] * inv, O[5] * inv, O[6] * inv, O[7] * inv);
    size_t base = ((size_t)(b * SEQ + q0 + q)) * DIMC + h * HDIM + d8;
    *(float4*)&ao[base] = o0;
    *(float4*)&ao[base + 4] = o1;
}

// ---------------------------------------------------------------------------
// Kernel 3: out = ao @ w_proj^T + b_proj (fp32, same tiling as kernel 1)
// ---------------------------------------------------------------------------
__global__ __launch_bounds__(256) void proj_gemm(
    const float* __restrict__ a,     // [4096][1024]
    const float* __restrict__ w,     // [1024][1024]
    const float* __restrict__ bias,  // [1024]
    float* __restrict__ out)         // [4096][1024]
{
    __shared__ float As[16][68];
    __shared__ float Bs[16][68];
    const int tid = threadIdx.x;
    const int tx = tid & 15, ty = tid >> 4;
    const int m0 = blockIdx.y * 64;
    const int j0 = blockIdx.x * 64;
    const int lr = tid >> 2;
    const int lk = (tid & 3) * 4;

    float acc[4][4] = {};

    for (int k0 = 0; k0 < DIMC; k0 += 16) {
        float4 av = *(const float4*)&a[(size_t)(m0 + lr) * DIMC + k0 + lk];
        float4 bv = *(const float4*)&w[(size_t)(j0 + lr) * DIMC + k0 + lk];
        __syncthreads();
        As[lk + 0][lr] = av.x; As[lk + 1][lr] = av.y;
        As[lk + 2][lr] = av.z; As[lk + 3][lr] = av.w;
        Bs[lk + 0][lr] = bv.x; Bs[lk + 1][lr] = bv.y;
        Bs[lk + 2][lr] = bv.z; Bs[lk + 3][lr] = bv.w;
        __syncthreads();
#pragma unroll
        for (int kk = 0; kk < 16; ++kk) {
            float4 a4 = *(const float4*)&As[kk][ty * 4];
            float4 b4 = *(const float4*)&Bs[kk][tx * 4];
            float ar[4] = {a4.x, a4.y, a4.z, a4.w};
            float br[4] = {b4.x, b4.y, b4.z, b4.w};
#pragma unroll
            for (int ii = 0; ii < 4; ++ii)
#pragma unroll
                for (int jj = 0; jj < 4; ++jj)
                    acc[ii][jj] += ar[ii] * br[jj];
        }
    }

    const int j = j0 + tx * 4;
    const float4 bb = *(const float4*)&bias[j];
#pragma unroll
    for (int ii = 0; ii < 4; ++ii) {
        const int m = m0 + ty * 4 + ii;
        float4 o = make_float4(acc[ii][0] + bb.x, acc[ii][1] + bb.y,
                               acc[ii][2] + bb.z, acc[ii][3] + bb.w);
        *(float4*)&out[(size_t)m * DIMC + j] = o;
    }
}

// ---------------------------------------------------------------------------
extern "C" void kernel_launch(void* const* d_in, const int* in_sizes, int n_in,
                              void* d_out, int out_size, void* d_ws, size_t ws_size,
                              hipStream_t stream) {
    const float* x      = (const float*)d_in[0];
    const float* w_qkv  = (const float*)d_in[1];
    const float* b_qkv  = (const float*)d_in[2];
    const float* w_proj = (const float*)d_in[3];
    const float* b_proj = (const float*)d_in[4];
    float* out = (float*)d_out;
    float* ws  = (float*)d_ws;

    float* qkv = ws;                       // Q|K|V: 3 * 4194304 floats (48 MB)
    float* ao  = ws + 3 * QKVSZ;           // 4194304 floats (16 MB)

    dim3 g1(QKVN / 64, MTOT / 64);         // 48 x 64
    qkv_gemm<<<g1, 256, 0, stream>>>(x, w_qkv, b_qkv, qkv);

    dim3 g2(SEQ / 32, NHEADS, BATCH);      // 64 x 16 x 2
    attn_kernel<<<g2, 256, 0, stream>>>(ws, ao);

    dim3 g3(DIMC / 64, MTOT / 64);         // 16 x 64
    proj_gemm<<<g3, 256, 0, stream>>>(ao, w_proj, b_proj, out);
}

// Round 2
// 636.475 us; speedup vs baseline: 1.9274x; 1.9274x over previous
//
#include <hip/hip_runtime.h>
#include <math.h>

#define DIMC   1024
#define NHEADS 16
#define HDIM   64
#define BATCH  2
#define SEQ    2048
#define SCALE  0.125f

#define MTOT   (BATCH * SEQ)          // 4096 rows
#define QKVN   (3 * DIMC)             // 3072
#define QKVSZ  ((size_t)BATCH * NHEADS * SEQ * HDIM)  // 4194304 elems per tensor

typedef __attribute__((ext_vector_type(8))) short bf16x8;
typedef __attribute__((ext_vector_type(4))) short bf16x4;
typedef __attribute__((ext_vector_type(4))) float f32x4;

static __device__ inline short f2bf(float f) {
    union { float f; unsigned u; } v; v.f = f;
    unsigned r = v.u + 0x7fffu + ((v.u >> 16) & 1u);   // RNE
    return (short)(r >> 16);
}

// ---------------------------------------------------------------------------
// Kernel 1: qkv = x @ w_qkv^T + b_qkv (fp32 compute), epilogue emits bf16:
//   Q [B,H,N,D], K [B,H,N,D], Vt [B,H,D,N] (transposed for MFMA B-frags).
// ---------------------------------------------------------------------------
__global__ __launch_bounds__(256) void qkv_gemm(
    const float* __restrict__ x,     // [4096][1024]
    const float* __restrict__ w,     // [3072][1024]
    const float* __restrict__ bias,  // [3072]
    short* __restrict__ qkvb)        // ws: Q|K|Vt bf16
{
    __shared__ float As[16][68];
    __shared__ float Bs[16][68];
    const int tid = threadIdx.x;
    const int tx = tid & 15, ty = tid >> 4;
    const int m0 = blockIdx.y * 64;
    const int j0 = blockIdx.x * 64;
    const int lr = tid >> 2;
    const int lk = (tid & 3) * 4;

    float acc[4][4] = {};

    for (int k0 = 0; k0 < DIMC; k0 += 16) {
        float4 av = *(const float4*)&x[(size_t)(m0 + lr) * DIMC + k0 + lk];
        float4 bv = *(const float4*)&w[(size_t)(j0 + lr) * DIMC + k0 + lk];
        __syncthreads();
        As[lk + 0][lr] = av.x; As[lk + 1][lr] = av.y;
        As[lk + 2][lr] = av.z; As[lk + 3][lr] = av.w;
        Bs[lk + 0][lr] = bv.x; Bs[lk + 1][lr] = bv.y;
        Bs[lk + 2][lr] = bv.z; Bs[lk + 3][lr] = bv.w;
        __syncthreads();
#pragma unroll
        for (int kk = 0; kk < 16; ++kk) {
            float4 a = *(const float4*)&As[kk][ty * 4];
            float4 b = *(const float4*)&Bs[kk][tx * 4];
            float ar[4] = {a.x, a.y, a.z, a.w};
            float br[4] = {b.x, b.y, b.z, b.w};
#pragma unroll
            for (int ii = 0; ii < 4; ++ii)
#pragma unroll
                for (int jj = 0; jj < 4; ++jj)
                    acc[ii][jj] += ar[ii] * br[jj];
        }
    }

    const int j = j0 + tx * 4;
    const int s = j >> 10;            // 0:q 1:k 2:v  (uniform per block)
    const int r = j & 1023;
    const int h = r >> 6;
    const int dcol = r & 63;
    float bb[4] = { bias[j], bias[j + 1], bias[j + 2], bias[j + 3] };

    if (s < 2) {
        // Q/K: [B,H,N,64], 4 consecutive d per thread -> bf16x4 (8B) store
#pragma unroll
        for (int ii = 0; ii < 4; ++ii) {
            const int m = m0 + ty * 4 + ii;
            const int b = m >> 11, n = m & 2047;
            bf16x4 o;
            o[0] = f2bf(acc[ii][0] + bb[0]);
            o[1] = f2bf(acc[ii][1] + bb[1]);
            o[2] = f2bf(acc[ii][2] + bb[2]);
            o[3] = f2bf(acc[ii][3] + bb[3]);
            size_t base = (size_t)s * QKVSZ +
                          ((size_t)(b * NHEADS + h) * SEQ + n) * HDIM + dcol;
            *(bf16x4*)&qkvb[base] = o;
        }
    } else {
        // V transposed: [B,H,64,N]; pack 4 consecutive n per store
        const int m = m0 + ty * 4;
        const int b = m >> 11, n0 = m & 2047;
#pragma unroll
        for (int jj = 0; jj < 4; ++jj) {
            bf16x4 o;
            o[0] = f2bf(acc[0][jj] + bb[jj]);
            o[1] = f2bf(acc[1][jj] + bb[jj]);
            o[2] = f2bf(acc[2][jj] + bb[jj]);
            o[3] = f2bf(acc[3][jj] + bb[jj]);
            size_t base = 2 * QKVSZ +
                          ((size_t)(b * NHEADS + h) * HDIM + dcol + jj) * SEQ + n0;
            *(bf16x4*)&qkvb[base] = o;
        }
    }
}

// ---------------------------------------------------------------------------
// Kernel 2: MFMA flash attention (bf16 in, fp32 softmax/accumulate).
// Block = 256 thr = 4 waves. 64 queries/block (16/wave), 64-key tiles.
// mfma_f32_16x16x32_bf16: A[m=lane&15][k=quad*8+j], B[k=quad*8+j][n=lane&15],
// C/D: row=quad*4+reg, col=lane&15.
// ---------------------------------------------------------------------------
__global__ __launch_bounds__(256) void attn_mfma(
    const short* __restrict__ qkvb,  // Q|K|Vt bf16
    float* __restrict__ ao)          // [B,N,C] fp32
{
    __shared__ __attribute__((aligned(16))) short Ks[64][72];
    __shared__ __attribute__((aligned(16))) short Vts[64][72];
    __shared__ __attribute__((aligned(16))) short Ps[4][16][72];

    const int tid  = threadIdx.x;
    const int w    = tid >> 6;
    const int lane = tid & 63;
    const int quad = lane >> 4;
    const int lid  = lane & 15;

    const int q0 = blockIdx.x * 64;
    const int h  = blockIdx.y;
    const int b  = blockIdx.z;

    const short* Qh  = qkvb + ((size_t)(b * NHEADS + h) * SEQ) * HDIM;
    const short* Kh  = Qh + QKVSZ;
    const short* Vth = qkvb + 2 * QKVSZ + (size_t)(b * NHEADS + h) * HDIM * SEQ;

    // Q A-fragments straight from global (per-wave 16-row strip)
    const int qrow = q0 + w * 16 + lid;
    bf16x8 aQ0 = *(const bf16x8*)&Qh[(size_t)qrow * HDIM + 0 * 32 + quad * 8];
    bf16x8 aQ1 = *(const bf16x8*)&Qh[(size_t)qrow * HDIM + 1 * 32 + quad * 8];

    float m_i[4] = { -1e30f, -1e30f, -1e30f, -1e30f };
    float l_i[4] = {};
    f32x4 Oacc[4];
#pragma unroll
    for (int fb = 0; fb < 4; ++fb) Oacc[fb] = (f32x4){0.f, 0.f, 0.f, 0.f};

    const int sr = tid >> 2;          // staging row 0..63
    const int sc16 = (tid & 3) * 16;  // staging col segment

    for (int kb = 0; kb < SEQ / 64; ++kb) {
        __syncthreads();
        // Stage K tile [64 keys][64 d] and Vt tile [64 d][64 keys]
        {
            const short* kg = &Kh[(size_t)(kb * 64 + sr) * HDIM + sc16];
            const short* vg = &Vth[(size_t)sr * SEQ + kb * 64 + sc16];
            *(bf16x8*)&Ks[sr][sc16]      = *(const bf16x8*)&kg[0];
            *(bf16x8*)&Ks[sr][sc16 + 8]  = *(const bf16x8*)&kg[8];
            *(bf16x8*)&Vts[sr][sc16]     = *(const bf16x8*)&vg[0];
            *(bf16x8*)&Vts[sr][sc16 + 8] = *(const bf16x8*)&vg[8];
        }
        __syncthreads();

        // Sc = Q K^T * SCALE  -> 4 column blocks of 16 keys
        f32x4 sc[4];
#pragma unroll
        for (int nb = 0; nb < 4; ++nb) {
            bf16x8 bK0 = *(const bf16x8*)&Ks[nb * 16 + lid][0 * 32 + quad * 8];
            bf16x8 bK1 = *(const bf16x8*)&Ks[nb * 16 + lid][1 * 32 + quad * 8];
            f32x4 c = (f32x4){0.f, 0.f, 0.f, 0.f};
            c = __builtin_amdgcn_mfma_f32_16x16x32_bf16(aQ0, bK0, c, 0, 0, 0);
            c = __builtin_amdgcn_mfma_f32_16x16x32_bf16(aQ1, bK1, c, 0, 0, 0);
#pragma unroll
            for (int r = 0; r < 4; ++r) c[r] *= SCALE;
            sc[nb] = c;
        }

        // online softmax per row r (row = quad*4+r); 16 lanes of quad = cols
        float mx[4], alpha[4], psum[4];
#pragma unroll
        for (int r = 0; r < 4; ++r) {
            float m0v = fmaxf(fmaxf(sc[0][r], sc[1][r]), fmaxf(sc[2][r], sc[3][r]));
            m0v = fmaxf(m0v, __shfl_xor(m0v, 1));
            m0v = fmaxf(m0v, __shfl_xor(m0v, 2));
            m0v = fmaxf(m0v, __shfl_xor(m0v, 4));
            m0v = fmaxf(m0v, __shfl_xor(m0v, 8));
            const float m_new = fmaxf(m_i[r], m0v);
            alpha[r] = __expf(m_i[r] - m_new);
            m_i[r] = m_new;
            psum[r] = 0.f;
#pragma unroll
            for (int nb = 0; nb < 4; ++nb) {
                float p = __expf(sc[nb][r] - m_new);
                sc[nb][r] = p;
                psum[r] += p;
            }
        }
#pragma unroll
        for (int r = 0; r < 4; ++r) {
            float ps = psum[r];
            ps += __shfl_xor(ps, 1);
            ps += __shfl_xor(ps, 2);
            ps += __shfl_xor(ps, 4);
            ps += __shfl_xor(ps, 8);
            l_i[r] = l_i[r] * alpha[r] + ps;
        }

        // P (C-layout) -> LDS -> A-layout bf16
#pragma unroll
        for (int nb = 0; nb < 4; ++nb)
#pragma unroll
            for (int r = 0; r < 4; ++r)
                Ps[w][quad * 4 + r][nb * 16 + lid] = f2bf(sc[nb][r]);

        // rescale O
#pragma unroll
        for (int fb = 0; fb < 4; ++fb)
#pragma unroll
            for (int r = 0; r < 4; ++r) Oacc[fb][r] *= alpha[r];

        bf16x8 aP0 = *(const bf16x8*)&Ps[w][lid][0 * 32 + quad * 8];
        bf16x8 aP1 = *(const bf16x8*)&Ps[w][lid][1 * 32 + quad * 8];

#pragma unroll
        for (int fb = 0; fb < 4; ++fb) {
            bf16x8 bV0 = *(const bf16x8*)&Vts[fb * 16 + lid][0 * 32 + quad * 8];
            bf16x8 bV1 = *(const bf16x8*)&Vts[fb * 16 + lid][1 * 32 + quad * 8];
            Oacc[fb] = __builtin_amdgcn_mfma_f32_16x16x32_bf16(aP0, bV0, Oacc[fb], 0, 0, 0);
            Oacc[fb] = __builtin_amdgcn_mfma_f32_16x16x32_bf16(aP1, bV1, Oacc[fb], 0, 0, 0);
        }
    }

    // epilogue: O / l, write ao [B,N,C] fp32
    float inv[4];
#pragma unroll
    for (int r = 0; r < 4; ++r) inv[r] = 1.f / l_i[r];
#pragma unroll
    for (int r = 0; r < 4; ++r) {
        const int n = q0 + w * 16 + quad * 4 + r;
        size_t base = ((size_t)(b * SEQ + n)) * DIMC + h * HDIM + lid;
#pragma unroll
        for (int fb = 0; fb < 4; ++fb)
            ao[base + fb * 16] = Oacc[fb][r] * inv[r];
    }
}

// ---------------------------------------------------------------------------
// Kernel 3: out = ao @ w_proj^T + b_proj (fp32)
// ---------------------------------------------------------------------------
__global__ __launch_bounds__(256) void proj_gemm(
    const float* __restrict__ a,     // [4096][1024]
    const float* __restrict__ w,     // [1024][1024]
    const float* __restrict__ bias,  // [1024]
    float* __restrict__ out)         // [4096][1024]
{
    __shared__ float As[16][68];
    __shared__ float Bs[16][68];
    const int tid = threadIdx.x;
    const int tx = tid & 15, ty = tid >> 4;
    const int m0 = blockIdx.y * 64;
    const int j0 = blockIdx.x * 64;
    const int lr = tid >> 2;
    const int lk = (tid & 3) * 4;

    float acc[4][4] = {};

    for (int k0 = 0; k0 < DIMC; k0 += 16) {
        float4 av = *(const float4*)&a[(size_t)(m0 + lr) * DIMC + k0 + lk];
        float4 bv = *(const float4*)&w[(size_t)(j0 + lr) * DIMC + k0 + lk];
        __syncthreads();
        As[lk + 0][lr] = av.x; As[lk + 1][lr] = av.y;
        As[lk + 2][lr] = av.z; As[lk + 3][lr] = av.w;
        Bs[lk + 0][lr] = bv.x; Bs[lk + 1][lr] = bv.y;
        Bs[lk + 2][lr] = bv.z; Bs[lk + 3][lr] = bv.w;
        __syncthreads();
#pragma unroll
        for (int kk = 0; kk < 16; ++kk) {
            float4 a4 = *(const float4*)&As[kk][ty * 4];
            float4 b4 = *(const float4*)&Bs[kk][tx * 4];
            float ar[4] = {a4.x, a4.y, a4.z, a4.w};
            float br[4] = {b4.x, b4.y, b4.z, b4.w};
#pragma unroll
            for (int ii = 0; ii < 4; ++ii)
#pragma unroll
                for (int jj = 0; jj < 4; ++jj)
                    acc[ii][jj] += ar[ii] * br[jj];
        }
    }

    const int j = j0 + tx * 4;
    const float4 bb = *(const float4*)&bias[j];
#pragma unroll
    for (int ii = 0; ii < 4; ++ii) {
        const int m = m0 + ty * 4 + ii;
        float4 o = make_float4(acc[ii][0] + bb.x, acc[ii][1] + bb.y,
                               acc[ii][2] + bb.z, acc[ii][3] + bb.w);
        *(float4*)&out[(size_t)m * DIMC + j] = o;
    }
}

// ---------------------------------------------------------------------------
extern "C" void kernel_launch(void* const* d_in, const int* in_sizes, int n_in,
                              void* d_out, int out_size, void* d_ws, size_t ws_size,
                              hipStream_t stream) {
    const float* x      = (const float*)d_in[0];
    const float* w_qkv  = (const float*)d_in[1];
    const float* b_qkv  = (const float*)d_in[2];
    const float* w_proj = (const float*)d_in[3];
    const float* b_proj = (const float*)d_in[4];
    float* out = (float*)d_out;

    short* qkvb = (short*)d_ws;                 // Q|K|Vt bf16: 24 MB
    float* ao   = (float*)(qkvb + 3 * QKVSZ);   // 16 MB fp32

    dim3 g1(QKVN / 64, MTOT / 64);              // 48 x 64
    qkv_gemm<<<g1, 256, 0, stream>>>(x, w_qkv, b_qkv, qkvb);

    dim3 g2(SEQ / 64, NHEADS, BATCH);           // 32 x 16 x 2
    attn_mfma<<<g2, 256, 0, stream>>>(qkvb, ao);

    dim3 g3(DIMC / 64, MTOT / 64);              // 16 x 64
    proj_gemm<<<g3, 256, 0, stream>>>(ao, w_proj, b_proj, out);
}

// Round 3
// 277.064 us; speedup vs baseline: 4.4277x; 2.2972x over previous
//
#include <hip/hip_runtime.h>
#include <math.h>

#define DIMC   1024
#define NHEADS 16
#define HDIM   64
#define BATCH  2
#define SEQ    2048
#define SCALE  0.125f

#define MTOT   (BATCH * SEQ)          // 4096 rows
#define QKVN   (3 * DIMC)             // 3072
#define QKVSZ  ((size_t)BATCH * NHEADS * SEQ * HDIM)  // 4194304 elems per tensor

typedef __attribute__((ext_vector_type(8))) short bf16x8;
typedef __attribute__((ext_vector_type(4))) short bf16x4;
typedef __attribute__((ext_vector_type(4))) float f32x4;

static __device__ inline short f2bf(float f) {
    union { float f; unsigned u; } v; v.f = f;
    unsigned r = v.u + 0x7fffu + ((v.u >> 16) & 1u);   // RNE
    return (short)(r >> 16);
}

// ---------------------------------------------------------------------------
// fp32 -> bf16 cast (memory-bound)
// ---------------------------------------------------------------------------
__global__ __launch_bounds__(256) void cast_bf16(
    const float* __restrict__ in, short* __restrict__ out, int n)
{
    int i = (blockIdx.x * 256 + threadIdx.x) * 8;
    if (i >= n) return;
    float4 a = *(const float4*)&in[i];
    float4 b = *(const float4*)&in[i + 4];
    bf16x8 o;
    o[0] = f2bf(a.x); o[1] = f2bf(a.y); o[2] = f2bf(a.z); o[3] = f2bf(a.w);
    o[4] = f2bf(b.x); o[5] = f2bf(b.y); o[6] = f2bf(b.z); o[7] = f2bf(b.w);
    *(bf16x8*)&out[i] = o;
}

// ---------------------------------------------------------------------------
// m97-style MFMA K-loop: 128x128 tile, BK=32, 4 waves, 4x4 16x16x32 accs.
// A [M][1024], B [N][1024] bf16 K-major. LDS [128][32] unpadded (required by
// global_load_lds: staging byte offset == tid*16 == wave base + lane*16).
// ---------------------------------------------------------------------------
__device__ __forceinline__ void gload16(const void* g, void* l) {
    __builtin_amdgcn_global_load_lds(
        (const __attribute__((address_space(1))) unsigned*)g,
        (__attribute__((address_space(3))) unsigned*)l, 16, 0, 0);
}

__device__ __forceinline__ void mfma_kloop(
    const short* __restrict__ A, const short* __restrict__ B,
    int m0, int j0, short* Asm, short* Bsm, int tid, f32x4 acc[4][4])
{
    const int lane = tid & 63;
    const int w    = tid >> 6;
    const int quad = lane >> 4;
    const int lid  = lane & 15;
    const int wm = (w >> 1) * 64, wn = (w & 1) * 64;

    const int r0  = tid >> 2;          // staging row 0..63
    const int kc0 = (tid & 3) * 8;     // staging k-elem offset

    for (int k0 = 0; k0 < 1024; k0 += 32) {
        __syncthreads();               // prev tile's LDS reads done
        gload16(&A[(size_t)(m0 + r0) * 1024 + k0 + kc0],      &Asm[r0 * 32 + kc0]);
        gload16(&A[(size_t)(m0 + 64 + r0) * 1024 + k0 + kc0], &Asm[(64 + r0) * 32 + kc0]);
        gload16(&B[(size_t)(j0 + r0) * 1024 + k0 + kc0],      &Bsm[r0 * 32 + kc0]);
        gload16(&B[(size_t)(j0 + 64 + r0) * 1024 + k0 + kc0], &Bsm[(64 + r0) * 32 + kc0]);
        __syncthreads();               // vmcnt(0) drain -> tile resident

        bf16x8 af[4], bfr[4];
#pragma unroll
        for (int i = 0; i < 4; ++i)
            af[i] = *(const bf16x8*)&Asm[(wm + i * 16 + lid) * 32 + quad * 8];
#pragma unroll
        for (int j = 0; j < 4; ++j)
            bfr[j] = *(const bf16x8*)&Bsm[(wn + j * 16 + lid) * 32 + quad * 8];
#pragma unroll
        for (int i = 0; i < 4; ++i)
#pragma unroll
            for (int j = 0; j < 4; ++j)
                acc[i][j] = __builtin_amdgcn_mfma_f32_16x16x32_bf16(
                    af[i], bfr[j], acc[i][j], 0, 0, 0);
    }
}

// ---------------------------------------------------------------------------
// Kernel 1: qkv = x_bf @ w_qkv_bf^T + b (MFMA), scatter bf16 Q,K [B,H,N,D],
// Vt [B,H,D,N].
// ---------------------------------------------------------------------------
__global__ __launch_bounds__(256) void qkv_mfma(
    const short* __restrict__ xb,    // [4096][1024] bf16
    const short* __restrict__ wb,    // [3072][1024] bf16
    const float* __restrict__ bias,  // [3072] fp32
    short* __restrict__ qkvb)        // Q|K|Vt bf16
{
    __shared__ __attribute__((aligned(16))) short Asm[128 * 32];
    __shared__ __attribute__((aligned(16))) short Bsm[128 * 32];

    const int tid = threadIdx.x;
    const int m0 = blockIdx.y * 128;
    const int j0 = blockIdx.x * 128;

    f32x4 acc[4][4];
#pragma unroll
    for (int i = 0; i < 4; ++i)
#pragma unroll
        for (int j = 0; j < 4; ++j) acc[i][j] = (f32x4){0.f, 0.f, 0.f, 0.f};

    mfma_kloop(xb, wb, m0, j0, Asm, Bsm, tid, acc);

    const int lane = tid & 63;
    const int w    = tid >> 6;
    const int quad = lane >> 4;
    const int lid  = lane & 15;
    const int wm = (w >> 1) * 64, wn = (w & 1) * 64;
    const int s = j0 >> 10;            // uniform: 1024 % 128 == 0

    if (s < 2) {
#pragma unroll
        for (int jb = 0; jb < 4; ++jb) {
            const int jj = j0 + wn + jb * 16 + lid;
            const int hh = (jj & 1023) >> 6;
            const int dd = jj & 63;
            const float bv = bias[jj];
#pragma unroll
            for (int i = 0; i < 4; ++i)
#pragma unroll
                for (int r = 0; r < 4; ++r) {
                    const int mrow = m0 + wm + i * 16 + quad * 4 + r;
                    const int b_ = mrow >> 11, nn = mrow & 2047;
                    qkvb[(size_t)s * QKVSZ +
                         ((size_t)(b_ * NHEADS + hh) * SEQ + nn) * HDIM + dd] =
                        f2bf(acc[i][jb][r] + bv);
                }
        }
    } else {
#pragma unroll
        for (int jb = 0; jb < 4; ++jb) {
            const int jj = j0 + wn + jb * 16 + lid;
            const int hh = (jj & 1023) >> 6;
            const int dd = jj & 63;
            const float bv = bias[jj];
#pragma unroll
            for (int i = 0; i < 4; ++i) {
                const int mrow0 = m0 + wm + i * 16 + quad * 4;
                const int b_ = mrow0 >> 11, n0 = mrow0 & 2047;
                bf16x4 o;
#pragma unroll
                for (int r = 0; r < 4; ++r) o[r] = f2bf(acc[i][jb][r] + bv);
                *(bf16x4*)&qkvb[2 * QKVSZ +
                    ((size_t)(b_ * NHEADS + hh) * HDIM + dd) * SEQ + n0] = o;
            }
        }
    }
}

// ---------------------------------------------------------------------------
// Kernel 2: MFMA flash attention (bf16 in, fp32 softmax), bf16 out.
// ---------------------------------------------------------------------------
__global__ __launch_bounds__(256) void attn_mfma(
    const short* __restrict__ qkvb,  // Q|K|Vt bf16
    short* __restrict__ aob)         // [B,N,C] bf16
{
    __shared__ __attribute__((aligned(16))) short Ks[64][72];
    __shared__ __attribute__((aligned(16))) short Vts[64][72];
    __shared__ __attribute__((aligned(16))) short Ps[4][16][72];

    const int tid  = threadIdx.x;
    const int w    = tid >> 6;
    const int lane = tid & 63;
    const int quad = lane >> 4;
    const int lid  = lane & 15;

    const int q0 = blockIdx.x * 64;
    const int h  = blockIdx.y;
    const int b  = blockIdx.z;

    const short* Qh  = qkvb + ((size_t)(b * NHEADS + h) * SEQ) * HDIM;
    const short* Kh  = Qh + QKVSZ;
    const short* Vth = qkvb + 2 * QKVSZ + (size_t)(b * NHEADS + h) * HDIM * SEQ;

    const int qrow = q0 + w * 16 + lid;
    bf16x8 aQ0 = *(const bf16x8*)&Qh[(size_t)qrow * HDIM + 0 * 32 + quad * 8];
    bf16x8 aQ1 = *(const bf16x8*)&Qh[(size_t)qrow * HDIM + 1 * 32 + quad * 8];

    float m_i[4] = { -1e30f, -1e30f, -1e30f, -1e30f };
    float l_i[4] = {};
    f32x4 Oacc[4];
#pragma unroll
    for (int fb = 0; fb < 4; ++fb) Oacc[fb] = (f32x4){0.f, 0.f, 0.f, 0.f};

    const int sr = tid >> 2;
    const int sc16 = (tid & 3) * 16;

    for (int kb = 0; kb < SEQ / 64; ++kb) {
        __syncthreads();
        {
            const short* kg = &Kh[(size_t)(kb * 64 + sr) * HDIM + sc16];
            const short* vg = &Vth[(size_t)sr * SEQ + kb * 64 + sc16];
            *(bf16x8*)&Ks[sr][sc16]      = *(const bf16x8*)&kg[0];
            *(bf16x8*)&Ks[sr][sc16 + 8]  = *(const bf16x8*)&kg[8];
            *(bf16x8*)&Vts[sr][sc16]     = *(const bf16x8*)&vg[0];
            *(bf16x8*)&Vts[sr][sc16 + 8] = *(const bf16x8*)&vg[8];
        }
        __syncthreads();

        f32x4 sc[4];
#pragma unroll
        for (int nb = 0; nb < 4; ++nb) {
            bf16x8 bK0 = *(const bf16x8*)&Ks[nb * 16 + lid][0 * 32 + quad * 8];
            bf16x8 bK1 = *(const bf16x8*)&Ks[nb * 16 + lid][1 * 32 + quad * 8];
            f32x4 c = (f32x4){0.f, 0.f, 0.f, 0.f};
            c = __builtin_amdgcn_mfma_f32_16x16x32_bf16(aQ0, bK0, c, 0, 0, 0);
            c = __builtin_amdgcn_mfma_f32_16x16x32_bf16(aQ1, bK1, c, 0, 0, 0);
#pragma unroll
            for (int r = 0; r < 4; ++r) c[r] *= SCALE;
            sc[nb] = c;
        }

        float alpha[4], psum[4];
#pragma unroll
        for (int r = 0; r < 4; ++r) {
            float m0v = fmaxf(fmaxf(sc[0][r], sc[1][r]), fmaxf(sc[2][r], sc[3][r]));
            m0v = fmaxf(m0v, __shfl_xor(m0v, 1));
            m0v = fmaxf(m0v, __shfl_xor(m0v, 2));
            m0v = fmaxf(m0v, __shfl_xor(m0v, 4));
            m0v = fmaxf(m0v, __shfl_xor(m0v, 8));
            const float m_new = fmaxf(m_i[r], m0v);
            alpha[r] = __expf(m_i[r] - m_new);
            m_i[r] = m_new;
            psum[r] = 0.f;
#pragma unroll
            for (int nb = 0; nb < 4; ++nb) {
                float p = __expf(sc[nb][r] - m_new);
                sc[nb][r] = p;
                psum[r] += p;
            }
        }
#pragma unroll
        for (int r = 0; r < 4; ++r) {
            float ps = psum[r];
            ps += __shfl_xor(ps, 1);
            ps += __shfl_xor(ps, 2);
            ps += __shfl_xor(ps, 4);
            ps += __shfl_xor(ps, 8);
            l_i[r] = l_i[r] * alpha[r] + ps;
        }

#pragma unroll
        for (int nb = 0; nb < 4; ++nb)
#pragma unroll
            for (int r = 0; r < 4; ++r)
                Ps[w][quad * 4 + r][nb * 16 + lid] = f2bf(sc[nb][r]);

#pragma unroll
        for (int fb = 0; fb < 4; ++fb)
#pragma unroll
            for (int r = 0; r < 4; ++r) Oacc[fb][r] *= alpha[r];

        bf16x8 aP0 = *(const bf16x8*)&Ps[w][lid][0 * 32 + quad * 8];
        bf16x8 aP1 = *(const bf16x8*)&Ps[w][lid][1 * 32 + quad * 8];

#pragma unroll
        for (int fb = 0; fb < 4; ++fb) {
            bf16x8 bV0 = *(const bf16x8*)&Vts[fb * 16 + lid][0 * 32 + quad * 8];
            bf16x8 bV1 = *(const bf16x8*)&Vts[fb * 16 + lid][1 * 32 + quad * 8];
            Oacc[fb] = __builtin_amdgcn_mfma_f32_16x16x32_bf16(aP0, bV0, Oacc[fb], 0, 0, 0);
            Oacc[fb] = __builtin_amdgcn_mfma_f32_16x16x32_bf16(aP1, bV1, Oacc[fb], 0, 0, 0);
        }
    }

    float inv[4];
#pragma unroll
    for (int r = 0; r < 4; ++r) inv[r] = 1.f / l_i[r];
#pragma unroll
    for (int r = 0; r < 4; ++r) {
        const int n = q0 + w * 16 + quad * 4 + r;
        size_t base = ((size_t)(b * SEQ + n)) * DIMC + h * HDIM + lid;
#pragma unroll
        for (int fb = 0; fb < 4; ++fb)
            aob[base + fb * 16] = f2bf(Oacc[fb][r] * inv[r]);
    }
}

// ---------------------------------------------------------------------------
// Kernel 3: out = ao_bf @ w_proj_bf^T + b_proj (MFMA), fp32 out
// ---------------------------------------------------------------------------
__global__ __launch_bounds__(256) void proj_mfma(
    const short* __restrict__ ab,    // [4096][1024] bf16
    const short* __restrict__ wb,    // [1024][1024] bf16
    const float* __restrict__ bias,  // [1024] fp32
    float* __restrict__ out)         // [4096][1024] fp32
{
    __shared__ __attribute__((aligned(16))) short Asm[128 * 32];
    __shared__ __attribute__((aligned(16))) short Bsm[128 * 32];

    const int tid = threadIdx.x;
    const int m0 = blockIdx.y * 128;
    const int j0 = blockIdx.x * 128;

    f32x4 acc[4][4];
#pragma unroll
    for (int i = 0; i < 4; ++i)
#pragma unroll
        for (int j = 0; j < 4; ++j) acc[i][j] = (f32x4){0.f, 0.f, 0.f, 0.f};

    mfma_kloop(ab, wb, m0, j0, Asm, Bsm, tid, acc);

    const int lane = tid & 63;
    const int w    = tid >> 6;
    const int quad = lane >> 4;
    const int lid  = lane & 15;
    const int wm = (w >> 1) * 64, wn = (w & 1) * 64;

#pragma unroll
    for (int jb = 0; jb < 4; ++jb) {
        const int jj = j0 + wn + jb * 16 + lid;
        const float bv = bias[jj];
#pragma unroll
        for (int i = 0; i < 4; ++i)
#pragma unroll
            for (int r = 0; r < 4; ++r) {
                const int mrow = m0 + wm + i * 16 + quad * 4 + r;
                out[(size_t)mrow * DIMC + jj] = acc[i][jb][r] + bv;
            }
    }
}

// ---------------------------------------------------------------------------
extern "C" void kernel_launch(void* const* d_in, const int* in_sizes, int n_in,
                              void* d_out, int out_size, void* d_ws, size_t ws_size,
                              hipStream_t stream) {
    const float* x      = (const float*)d_in[0];
    const float* w_qkv  = (const float*)d_in[1];
    const float* b_qkv  = (const float*)d_in[2];
    const float* w_proj = (const float*)d_in[3];
    const float* b_proj = (const float*)d_in[4];
    float* out = (float*)d_out;

    short* qkvb   = (short*)d_ws;                  // 3*QKVSZ
    short* xb     = qkvb + 3 * QKVSZ;              // 4.2M
    short* wqkvb  = xb + (size_t)MTOT * DIMC;      // 3.1M
    short* wprojb = wqkvb + (size_t)QKVN * DIMC;   // 1.0M
    short* aob    = wprojb + (size_t)DIMC * DIMC;  // 4.2M

    const int nx = MTOT * DIMC, nwq = QKVN * DIMC, nwp = DIMC * DIMC;
    cast_bf16<<<nx / 2048, 256, 0, stream>>>(x, xb, nx);
    cast_bf16<<<nwq / 2048, 256, 0, stream>>>(w_qkv, wqkvb, nwq);
    cast_bf16<<<nwp / 2048, 256, 0, stream>>>(w_proj, wprojb, nwp);

    dim3 g1(QKVN / 128, MTOT / 128);               // 24 x 32
    qkv_mfma<<<g1, 256, 0, stream>>>(xb, wqkvb, b_qkv, qkvb);

    dim3 g2(SEQ / 64, NHEADS, BATCH);              // 32 x 16 x 2
    attn_mfma<<<g2, 256, 0, stream>>>(qkvb, aob);

    dim3 g3(DIMC / 128, MTOT / 128);               // 8 x 32
    proj_mfma<<<g3, 256, 0, stream>>>(aob, wprojb, b_proj, out);
}